// Round 1
// baseline (517.621 us; speedup 1.0000x reference)
//
#include <hip/hip_runtime.h>
#include <hip/hip_bf16.h>
#include <cstdint>

// Shapes
#define BB 4
#define TT 256
#define UB 64
#define AA 512
#define DD 640
#define HH 640
#define VV 1024

typedef __attribute__((ext_vector_type(8))) short short8;
typedef __attribute__((ext_vector_type(4))) float f32x4;

__device__ __forceinline__ unsigned short f2bf(float f) {
    unsigned u = __builtin_bit_cast(unsigned, f);
    u += 0x7fffu + ((u >> 16) & 1u);   // RNE
    return (unsigned short)(u >> 16);
}

__device__ __forceinline__ float fast_tanh(float x) {
    // tanh(x) = 1 - 2/(1+e^{2x}); saturates correctly at +-inf
    return 1.0f - 2.0f / (1.0f + __expf(2.0f * x));
}

// ---------------------------------------------------------------------------
// Pack W_out (640x1024 f32) -> bf16 in MFMA B-fragment order:
// element (kb, nb, n', hi, j) = W[kb*32 + hi*8 + j][nb*16 + n']
// flat offset = (kb*64+nb)*512 + n'*32 + hi*8 + j      (bf16 elements)
// A wave's 8-elem B-frag for (kb, nb) is then lane-contiguous 16B chunks of
// one 1KiB block -> perfectly coalesced global_load_dwordx4.
// ---------------------------------------------------------------------------
__global__ __launch_bounds__(256) void kpack(const float* __restrict__ W,
                                             unsigned short* __restrict__ wp) {
    __shared__ float tile[32][64];
    const int kb  = blockIdx.x >> 4;   // 0..19
    const int nbg = blockIdx.x & 15;   // 0..15  (covers 4 nb each)
    const int tid = threadIdx.x;
#pragma unroll
    for (int i = 0; i < 8; ++i) {
        int idx = tid + (i << 8);
        int r = idx >> 6, c = idx & 63;
        tile[r][c] = W[(size_t)(kb * 32 + r) * VV + nbg * 64 + c];
    }
    __syncthreads();
    const int hi  = tid & 3;
    const int np  = (tid >> 2) & 15;
    const int nbl = tid >> 6;
    __align__(16) unsigned short v[8];
#pragma unroll
    for (int j = 0; j < 8; ++j)
        v[j] = f2bf(tile[hi * 8 + j][nbl * 16 + np]);
    size_t off = (size_t)((kb * 64 + nbg * 4 + nbl) * 512 + np * 32 + hi * 8);
    *reinterpret_cast<uint4*>(wp + off) = *reinterpret_cast<const uint4*>(v);
}

// ---------------------------------------------------------------------------
// Small fp32 projections: enc (1024x512 @ 512x640) and dec (256x640 @ 640x640)
// One block = 8 rows staged in LDS; 640 threads = one output column each.
// blocks 0..127: enc,  128..159: dec
// ---------------------------------------------------------------------------
__global__ __launch_bounds__(640) void kproj(
    const float* __restrict__ enc_in, const float* __restrict__ dec_in,
    const float* __restrict__ We, const float* __restrict__ be,
    const float* __restrict__ Wd, const float* __restrict__ bd,
    float* __restrict__ enc_out, float* __restrict__ dec_out) {
    __shared__ float rows[8][DD];
    const int bi = blockIdx.x;
    const float *in, *W, *bias;
    float* out;
    int K, row0;
    if (bi < 128) { in = enc_in; W = We; bias = be; out = enc_out; K = AA; row0 = bi * 8; }
    else          { in = dec_in; W = Wd; bias = bd; out = dec_out; K = DD; row0 = (bi - 128) * 8; }
    const int tid = threadIdx.x;
    for (int r = 0; r < 8; ++r)
        for (int k = tid; k < K; k += 640)
            rows[r][k] = in[(size_t)(row0 + r) * K + k];
    __syncthreads();
    const int col = tid;  // 0..639
    float acc[8] = {0.f, 0.f, 0.f, 0.f, 0.f, 0.f, 0.f, 0.f};
    for (int k = 0; k < K; ++k) {
        float w = W[(size_t)k * HH + col];
#pragma unroll
        for (int r = 0; r < 8; ++r) acc[r] = fmaf(rows[r][k], w, acc[r]);
    }
    float bbv = bias[col];
#pragma unroll
    for (int r = 0; r < 8; ++r)
        out[(size_t)(row0 + r) * HH + col] = acc[r] + bbv;
}

// ---------------------------------------------------------------------------
// Main fused kernel. One block per (b,t): 64 u-rows x 1024 vocab.
// 8 waves, wave w owns cols [w*128, w*128+128). 16x16x32 bf16 MFMA,
// per wave: 4 M-frags x 8 N-frags -> 128 acc VGPRs.
// z tile in LDS as bf16 [64][640], XOR-swizzled byte^=((row&7)<<4).
// Epilogue: fused log-softmax (shfl + 2KB LDS cross-wave reduce).
// ---------------------------------------------------------------------------
__global__ __launch_bounds__(512, 2) void kmain(
    const float* __restrict__ encp, const float* __restrict__ decp,
    const unsigned short* __restrict__ wp, const float* __restrict__ bo,
    float* __restrict__ out) {
    __shared__ __align__(16) unsigned char zb[UB * 1280];  // 80 KiB
    __shared__ __align__(16) float red1[UB][8];
    __shared__ __align__(16) float red2[UB][8];
    const int bt   = blockIdx.x;      // 0..1023  == b*256 + t
    const int b    = bt >> 8;
    const int tid  = threadIdx.x;
    const int lane = tid & 63;
    const int wv   = tid >> 6;        // 0..7
    const int lo   = lane & 15;
    const int hi   = lane >> 4;
    const float* encr = encp + (size_t)bt * HH;
    const float* decr = decp + (size_t)b * UB * HH;

    // ---- phase 1: z = tanh(enc + dec) -> bf16 LDS (swizzled) ----
#pragma unroll
    for (int i = 0; i < 10; ++i) {
        int c  = tid + i * 512;       // 0..5119 chunks of 8
        int u  = c / 80;
        int h0 = (c - u * 80) * 8;
        const float4* dp = reinterpret_cast<const float4*>(decr + (size_t)u * HH + h0);
        const float4* ep = reinterpret_cast<const float4*>(encr + h0);
        float4 d0 = dp[0], d1 = dp[1];
        float4 e0 = ep[0], e1 = ep[1];
        __align__(16) unsigned short zs[8];
        zs[0] = f2bf(fast_tanh(e0.x + d0.x));
        zs[1] = f2bf(fast_tanh(e0.y + d0.y));
        zs[2] = f2bf(fast_tanh(e0.z + d0.z));
        zs[3] = f2bf(fast_tanh(e0.w + d0.w));
        zs[4] = f2bf(fast_tanh(e1.x + d1.x));
        zs[5] = f2bf(fast_tanh(e1.y + d1.y));
        zs[6] = f2bf(fast_tanh(e1.z + d1.z));
        zs[7] = f2bf(fast_tanh(e1.w + d1.w));
        unsigned addr = (unsigned)(u * 1280 + h0 * 2) ^ ((unsigned)(u & 7) << 4);
        *reinterpret_cast<uint4*>(zb + addr) = *reinterpret_cast<const uint4*>(zs);
    }
    __syncthreads();

    // ---- phase 2: GEMM  (64 x 640) @ (640 x 1024) in bf16 MFMA ----
    f32x4 acc[4][8];
#pragma unroll
    for (int mf = 0; mf < 4; ++mf)
#pragma unroll
        for (int nf = 0; nf < 8; ++nf)
            acc[mf][nf] = (f32x4){0.f, 0.f, 0.f, 0.f};
    const int nb0 = wv * 8;
#pragma unroll 2
    for (int kb = 0; kb < 20; ++kb) {
        short8 af[4];
#pragma unroll
        for (int mf = 0; mf < 4; ++mf) {
            int row = mf * 16 + lo;
            unsigned addr = (unsigned)(row * 1280 + kb * 64 + hi * 16) ^
                            ((unsigned)(row & 7) << 4);
            af[mf] = *reinterpret_cast<const short8*>(zb + addr);
        }
#pragma unroll
        for (int nf = 0; nf < 8; ++nf) {
            const unsigned short* p =
                wp + (size_t)((kb * 64 + nb0 + nf) * 512 + lo * 32 + hi * 8);
            short8 bf = *reinterpret_cast<const short8*>(p);
#pragma unroll
            for (int mf = 0; mf < 4; ++mf)
                acc[mf][nf] = __builtin_amdgcn_mfma_f32_16x16x32_bf16(
                    af[mf], bf, acc[mf][nf], 0, 0, 0);
        }
    }

    // ---- phase 3: +bias, fused log-softmax, store ----
    const int n0 = wv * 128;
    float bbv[8];
#pragma unroll
    for (int nf = 0; nf < 8; ++nf) bbv[nf] = bo[n0 + nf * 16 + lo];
#pragma unroll
    for (int mf = 0; mf < 4; ++mf)
#pragma unroll
        for (int nf = 0; nf < 8; ++nf) {
            acc[mf][nf][0] += bbv[nf];
            acc[mf][nf][1] += bbv[nf];
            acc[mf][nf][2] += bbv[nf];
            acc[mf][nf][3] += bbv[nf];
        }

    // row max: reduce over nf (in-lane) then over 16-lane col group, then waves
#pragma unroll
    for (int mf = 0; mf < 4; ++mf)
#pragma unroll
        for (int rg = 0; rg < 4; ++rg) {
            float v = acc[mf][0][rg];
#pragma unroll
            for (int nf = 1; nf < 8; ++nf) v = fmaxf(v, acc[mf][nf][rg]);
            v = fmaxf(v, __shfl_xor(v, 1));
            v = fmaxf(v, __shfl_xor(v, 2));
            v = fmaxf(v, __shfl_xor(v, 4));
            v = fmaxf(v, __shfl_xor(v, 8));
            if (lo == 0) red1[mf * 16 + hi * 4 + rg][wv] = v;
        }
    __syncthreads();
    float rmax[4][4];
#pragma unroll
    for (int mf = 0; mf < 4; ++mf)
#pragma unroll
        for (int rg = 0; rg < 4; ++rg) {
            int row = mf * 16 + hi * 4 + rg;
            const float4* r4 = reinterpret_cast<const float4*>(&red1[row][0]);
            float4 x = r4[0], y = r4[1];
            rmax[mf][rg] = fmaxf(fmaxf(fmaxf(x.x, x.y), fmaxf(x.z, x.w)),
                                 fmaxf(fmaxf(y.x, y.y), fmaxf(y.z, y.w)));
        }
    // sum of exp
#pragma unroll
    for (int mf = 0; mf < 4; ++mf)
#pragma unroll
        for (int rg = 0; rg < 4; ++rg) {
            float s = 0.f;
#pragma unroll
            for (int nf = 0; nf < 8; ++nf)
                s += __expf(acc[mf][nf][rg] - rmax[mf][rg]);
            s += __shfl_xor(s, 1);
            s += __shfl_xor(s, 2);
            s += __shfl_xor(s, 4);
            s += __shfl_xor(s, 8);
            if (lo == 0) red2[mf * 16 + hi * 4 + rg][wv] = s;
        }
    __syncthreads();
    float lz[4][4];
#pragma unroll
    for (int mf = 0; mf < 4; ++mf)
#pragma unroll
        for (int rg = 0; rg < 4; ++rg) {
            int row = mf * 16 + hi * 4 + rg;
            const float4* r4 = reinterpret_cast<const float4*>(&red2[row][0]);
            float4 x = r4[0], y = r4[1];
            float s = (x.x + x.y) + (x.z + x.w) + (y.x + y.y) + (y.z + y.w);
            lz[mf][rg] = rmax[mf][rg] + __logf(s);
        }
    // store: out[bt*64 + row][n0 + nf*16 + lo]
    float* outbase = out + (size_t)bt * UB * VV;
#pragma unroll
    for (int mf = 0; mf < 4; ++mf)
#pragma unroll
        for (int rg = 0; rg < 4; ++rg) {
            int row = mf * 16 + hi * 4 + rg;
            float* orow = outbase + (size_t)row * VV + n0 + lo;
#pragma unroll
            for (int nf = 0; nf < 8; ++nf)
                orow[nf * 16] = acc[mf][nf][rg] - lz[mf][rg];
        }
}

// ---------------------------------------------------------------------------
extern "C" void kernel_launch(void* const* d_in, const int* in_sizes, int n_in,
                              void* d_out, int out_size, void* d_ws, size_t ws_size,
                              hipStream_t stream) {
    const float* enc_in = (const float*)d_in[0];
    const float* dec_in = (const float*)d_in[1];
    const float* We     = (const float*)d_in[2];
    const float* be     = (const float*)d_in[3];
    const float* Wd     = (const float*)d_in[4];
    const float* bd     = (const float*)d_in[5];
    const float* Wo     = (const float*)d_in[6];
    const float* bo     = (const float*)d_in[7];
    float* out = (float*)d_out;

    float* ws   = (float*)d_ws;
    float* encp = ws;                        // 1024*640 f32
    float* decp = ws + 1024 * 640;           // 256*640  f32
    unsigned short* wp = (unsigned short*)(ws + 1024 * 640 + 256 * 640);  // 640*1024 bf16

    kpack<<<320, 256, 0, stream>>>(Wo, wp);
    kproj<<<160, 640, 0, stream>>>(enc_in, dec_in, We, be, Wd, bd, encp, decp);
    kmain<<<1024, 512, 0, stream>>>(encp, decp, wp, bo, out);
}

// Round 2
// 475.680 us; speedup vs baseline: 1.0882x; 1.0882x over previous
//
#include <hip/hip_runtime.h>
#include <hip/hip_bf16.h>
#include <cstdint>

// Shapes
#define BB 4
#define TT 256
#define UB 64
#define AA 512
#define DD 640
#define HH 640
#define VV 1024

typedef __attribute__((ext_vector_type(8))) short short8;
typedef __attribute__((ext_vector_type(4))) float f32x4;

__device__ __forceinline__ unsigned short f2bf(float f) {
    unsigned u = __builtin_bit_cast(unsigned, f);
    u += 0x7fffu + ((u >> 16) & 1u);   // RNE
    return (unsigned short)(u >> 16);
}

__device__ __forceinline__ float fast_tanh(float x) {
    return 1.0f - 2.0f / (1.0f + __expf(2.0f * x));
}

// ---------------------------------------------------------------------------
// Pack W_out (640x1024 f32) -> bf16 in MFMA B-fragment order.
// ---------------------------------------------------------------------------
__global__ __launch_bounds__(256) void kpack(const float* __restrict__ W,
                                             unsigned short* __restrict__ wp) {
    __shared__ float tile[32][64];
    const int kb  = blockIdx.x >> 4;   // 0..19
    const int nbg = blockIdx.x & 15;   // 0..15
    const int tid = threadIdx.x;
#pragma unroll
    for (int i = 0; i < 8; ++i) {
        int idx = tid + (i << 8);
        int r = idx >> 6, c = idx & 63;
        tile[r][c] = W[(size_t)(kb * 32 + r) * VV + nbg * 64 + c];
    }
    __syncthreads();
    const int hi  = tid & 3;
    const int np  = (tid >> 2) & 15;
    const int nbl = tid >> 6;
    __align__(16) unsigned short v[8];
#pragma unroll
    for (int j = 0; j < 8; ++j)
        v[j] = f2bf(tile[hi * 8 + j][nbl * 16 + np]);
    size_t off = (size_t)((kb * 64 + nbg * 4 + nbl) * 512 + np * 32 + hi * 8);
    *reinterpret_cast<uint4*>(wp + off) = *reinterpret_cast<const uint4*>(v);
}

// ---------------------------------------------------------------------------
// Tiled fp32 projections. 64x64 tile, BK=16, 256 threads, 4x4 micro-tile,
// register-prefetched global->LDS staging.
// blocks 0..159: enc (1024x640, K=512, 16x10 tiles)
// blocks 160..199: dec (256x640, K=640, 4x10 tiles)
// ---------------------------------------------------------------------------
__global__ __launch_bounds__(256) void kproj(
    const float* __restrict__ enc_in, const float* __restrict__ dec_in,
    const float* __restrict__ We, const float* __restrict__ be,
    const float* __restrict__ Wd, const float* __restrict__ bd,
    float* __restrict__ enc_out, float* __restrict__ dec_out) {
    __shared__ float As[16][68];
    __shared__ float Bs[16][68];
    const int bi = blockIdx.x;
    const float *A, *W, *bias;
    float* C;
    int K, bm, bn;
    if (bi < 160) { A = enc_in; W = We; bias = be; C = enc_out; K = AA; bm = bi / 10; bn = bi - bm * 10; }
    else { int bj = bi - 160; A = dec_in; W = Wd; bias = bd; C = dec_out; K = DD; bm = bj / 10; bn = bj - bm * 10; }
    const int tid  = threadIdx.x;
    const int row0 = bm * 64, n0 = bn * 64;
    const int tm = tid & 15, tn = tid >> 4;          // micro-tile coords
    const int am = tid & 63, akq = tid >> 6;          // A-stage coords
    const int bk = tid >> 4, bn4 = (tid & 15) * 4;    // B-stage coords

    float acc[4][4] = {};
    float4 a4 = *reinterpret_cast<const float4*>(A + (size_t)(row0 + am) * K + akq * 4);
    float4 b4 = *reinterpret_cast<const float4*>(W + (size_t)bk * HH + n0 + bn4);

    for (int k0 = 0; k0 < K; k0 += 16) {
        As[akq * 4 + 0][am] = a4.x;
        As[akq * 4 + 1][am] = a4.y;
        As[akq * 4 + 2][am] = a4.z;
        As[akq * 4 + 3][am] = a4.w;
        *reinterpret_cast<float4*>(&Bs[bk][bn4]) = b4;
        __syncthreads();
        if (k0 + 16 < K) {
            a4 = *reinterpret_cast<const float4*>(A + (size_t)(row0 + am) * K + k0 + 16 + akq * 4);
            b4 = *reinterpret_cast<const float4*>(W + (size_t)(k0 + 16 + bk) * HH + n0 + bn4);
        }
#pragma unroll
        for (int kk = 0; kk < 16; ++kk) {
            float4 av = *reinterpret_cast<const float4*>(&As[kk][tm * 4]);
            float4 bv = *reinterpret_cast<const float4*>(&Bs[kk][tn * 4]);
            float a_[4] = {av.x, av.y, av.z, av.w};
            float b_[4] = {bv.x, bv.y, bv.z, bv.w};
#pragma unroll
            for (int i = 0; i < 4; ++i)
#pragma unroll
                for (int j = 0; j < 4; ++j)
                    acc[i][j] = fmaf(a_[i], b_[j], acc[i][j]);
        }
        __syncthreads();
    }
    float bv0 = bias[n0 + tn * 4 + 0], bv1 = bias[n0 + tn * 4 + 1];
    float bv2 = bias[n0 + tn * 4 + 2], bv3 = bias[n0 + tn * 4 + 3];
#pragma unroll
    for (int i = 0; i < 4; ++i) {
        float4 o = {acc[i][0] + bv0, acc[i][1] + bv1, acc[i][2] + bv2, acc[i][3] + bv3};
        *reinterpret_cast<float4*>(C + (size_t)(row0 + tm * 4 + i) * HH + n0 + tn * 4) = o;
    }
}

// ---------------------------------------------------------------------------
// Main fused kernel. One block per (b,t): 64 u-rows x 1024 vocab, 8 waves.
// K split into two 320-wide halves so the z LDS tile is 40KB -> 2 blocks/CU.
// ---------------------------------------------------------------------------
__global__ __launch_bounds__(512, 2) void kmain(
    const float* __restrict__ encp, const float* __restrict__ decp,
    const unsigned short* __restrict__ wp, const float* __restrict__ bo,
    float* __restrict__ out) {
    __shared__ __align__(16) unsigned char zb[UB * 640];  // 40 KiB (bf16 [64][320])
    __shared__ __align__(16) float red1[UB][8];
    __shared__ __align__(16) float red2[UB][8];
    const int bt   = blockIdx.x;      // b*256 + t
    const int b    = bt >> 8;
    const int tid  = threadIdx.x;
    const int lane = tid & 63;
    const int wv   = tid >> 6;        // 0..7
    const int lo   = lane & 15;
    const int hi   = lane >> 4;
    const float* encr = encp + (size_t)bt * HH;
    const float* decr = decp + (size_t)b * UB * HH;
    const int nb0 = wv * 8;

    f32x4 acc[4][8];
#pragma unroll
    for (int mf = 0; mf < 4; ++mf)
#pragma unroll
        for (int nf = 0; nf < 8; ++nf)
            acc[mf][nf] = (f32x4){0.f, 0.f, 0.f, 0.f};

#pragma unroll
    for (int half = 0; half < 2; ++half) {
        // ---- tanh phase: z[:, half*320 : half*320+320] -> bf16 LDS ----
#pragma unroll
        for (int i = 0; i < 5; ++i) {
            int c  = tid + i * 512;       // 0..2559, chunks of 8
            int u  = c / 40;
            int h0 = (c - u * 40) * 8;    // 0..312
            const float4* dp = reinterpret_cast<const float4*>(decr + (size_t)u * HH + half * 320 + h0);
            const float4* ep = reinterpret_cast<const float4*>(encr + half * 320 + h0);
            float4 d0 = dp[0], d1 = dp[1];
            float4 e0 = ep[0], e1 = ep[1];
            __align__(16) unsigned short zs[8];
            zs[0] = f2bf(fast_tanh(e0.x + d0.x));
            zs[1] = f2bf(fast_tanh(e0.y + d0.y));
            zs[2] = f2bf(fast_tanh(e0.z + d0.z));
            zs[3] = f2bf(fast_tanh(e0.w + d0.w));
            zs[4] = f2bf(fast_tanh(e1.x + d1.x));
            zs[5] = f2bf(fast_tanh(e1.y + d1.y));
            zs[6] = f2bf(fast_tanh(e1.z + d1.z));
            zs[7] = f2bf(fast_tanh(e1.w + d1.w));
            unsigned addr = (unsigned)(u * 640 + h0 * 2) ^ ((unsigned)(u & 7) << 4);
            *reinterpret_cast<uint4*>(zb + addr) = *reinterpret_cast<const uint4*>(zs);
        }
        __syncthreads();

        // ---- GEMM over this half's 10 K-blocks ----
#pragma unroll
        for (int kb = 0; kb < 10; ++kb) {
            const int kbg = half * 10 + kb;
            short8 af[4];
#pragma unroll
            for (int mf = 0; mf < 4; ++mf) {
                int row = mf * 16 + lo;
                unsigned addr = (unsigned)(row * 640 + kb * 64 + hi * 16) ^
                                ((unsigned)(row & 7) << 4);
                af[mf] = *reinterpret_cast<const short8*>(zb + addr);
            }
#pragma unroll
            for (int nf = 0; nf < 8; ++nf) {
                const unsigned short* p =
                    wp + (size_t)((kbg * 64 + nb0 + nf) * 512 + lo * 32 + hi * 8);
                short8 bf = *reinterpret_cast<const short8*>(p);
#pragma unroll
                for (int mf = 0; mf < 4; ++mf)
                    acc[mf][nf] = __builtin_amdgcn_mfma_f32_16x16x32_bf16(
                        af[mf], bf, acc[mf][nf], 0, 0, 0);
            }
        }
        __syncthreads();   // zb reused by next half
    }

    // ---- epilogue: +bias, fused log-softmax, store ----
    const int n0 = wv * 128;
    float bbv[8];
#pragma unroll
    for (int nf = 0; nf < 8; ++nf) bbv[nf] = bo[n0 + nf * 16 + lo];
#pragma unroll
    for (int mf = 0; mf < 4; ++mf)
#pragma unroll
        for (int nf = 0; nf < 8; ++nf) {
            acc[mf][nf][0] += bbv[nf];
            acc[mf][nf][1] += bbv[nf];
            acc[mf][nf][2] += bbv[nf];
            acc[mf][nf][3] += bbv[nf];
        }

#pragma unroll
    for (int mf = 0; mf < 4; ++mf)
#pragma unroll
        for (int rg = 0; rg < 4; ++rg) {
            float v = acc[mf][0][rg];
#pragma unroll
            for (int nf = 1; nf < 8; ++nf) v = fmaxf(v, acc[mf][nf][rg]);
            v = fmaxf(v, __shfl_xor(v, 1));
            v = fmaxf(v, __shfl_xor(v, 2));
            v = fmaxf(v, __shfl_xor(v, 4));
            v = fmaxf(v, __shfl_xor(v, 8));
            if (lo == 0) red1[mf * 16 + hi * 4 + rg][wv] = v;
        }
    __syncthreads();
    float rmax[4][4];
#pragma unroll
    for (int mf = 0; mf < 4; ++mf)
#pragma unroll
        for (int rg = 0; rg < 4; ++rg) {
            int row = mf * 16 + hi * 4 + rg;
            const float4* r4 = reinterpret_cast<const float4*>(&red1[row][0]);
            float4 x = r4[0], y = r4[1];
            rmax[mf][rg] = fmaxf(fmaxf(fmaxf(x.x, x.y), fmaxf(x.z, x.w)),
                                 fmaxf(fmaxf(y.x, y.y), fmaxf(y.z, y.w)));
        }
#pragma unroll
    for (int mf = 0; mf < 4; ++mf)
#pragma unroll
        for (int rg = 0; rg < 4; ++rg) {
            float s = 0.f;
#pragma unroll
            for (int nf = 0; nf < 8; ++nf)
                s += __expf(acc[mf][nf][rg] - rmax[mf][rg]);
            s += __shfl_xor(s, 1);
            s += __shfl_xor(s, 2);
            s += __shfl_xor(s, 4);
            s += __shfl_xor(s, 8);
            if (lo == 0) red2[mf * 16 + hi * 4 + rg][wv] = s;
        }
    __syncthreads();
    float lz[4][4];
#pragma unroll
    for (int mf = 0; mf < 4; ++mf)
#pragma unroll
        for (int rg = 0; rg < 4; ++rg) {
            int row = mf * 16 + hi * 4 + rg;
            const float4* r4 = reinterpret_cast<const float4*>(&red2[row][0]);
            float4 x = r4[0], y = r4[1];
            float s = (x.x + x.y) + (x.z + x.w) + (y.x + y.y) + (y.z + y.w);
            lz[mf][rg] = rmax[mf][rg] + __logf(s);
        }
    float* outbase = out + (size_t)bt * UB * VV;
#pragma unroll
    for (int mf = 0; mf < 4; ++mf)
#pragma unroll
        for (int rg = 0; rg < 4; ++rg) {
            int row = mf * 16 + hi * 4 + rg;
            float* orow = outbase + (size_t)row * VV + n0 + lo;
#pragma unroll
            for (int nf = 0; nf < 8; ++nf)
                orow[nf * 16] = acc[mf][nf][rg] - lz[mf][rg];
        }
}

// ---------------------------------------------------------------------------
extern "C" void kernel_launch(void* const* d_in, const int* in_sizes, int n_in,
                              void* d_out, int out_size, void* d_ws, size_t ws_size,
                              hipStream_t stream) {
    const float* enc_in = (const float*)d_in[0];
    const float* dec_in = (const float*)d_in[1];
    const float* We     = (const float*)d_in[2];
    const float* be     = (const float*)d_in[3];
    const float* Wd     = (const float*)d_in[4];
    const float* bd     = (const float*)d_in[5];
    const float* Wo     = (const float*)d_in[6];
    const float* bo     = (const float*)d_in[7];
    float* out = (float*)d_out;

    float* ws   = (float*)d_ws;
    float* encp = ws;                        // 1024*640 f32
    float* decp = ws + 1024 * 640;           // 256*640  f32
    unsigned short* wp = (unsigned short*)(ws + 1024 * 640 + 256 * 640);  // 640*1024 bf16

    kpack<<<320, 256, 0, stream>>>(Wo, wp);
    kproj<<<200, 256, 0, stream>>>(enc_in, dec_in, We, be, Wd, bd, encp, decp);
    kmain<<<1024, 512, 0, stream>>>(encp, decp, wp, bo, out);
}